// Round 2
// baseline (605.175 us; speedup 1.0000x reference)
//
#include <hip/hip_runtime.h>

// ---------------------------------------------------------------------------
// MaskedMultiHeadAttention: B=2, T=2048, E=1024, H=16, D=64, WINDOW=256
//
// Input/output dtype is detected AT RUNTIME (device-side): a probe kernel
// classifies d_in[0]'s bit patterns as bf16-pairs vs fp32 words and writes a
// flag to ws; every downstream kernel canonicalizes through bf16 off that
// flag, and the last GEMM emits d_out as bf16 or fp32 accordingly.
//
// Pipeline:
//   0) detect dtype -> flag
//   1) canonicalize hidden/biases to bf16; transpose w_attn/w_proj to bf16
//   2) qkv = hidden @ w_attn + b_attn          (MFMA bf16 GEMM, m97 structure)
//   3) windowed causal attention -> attn_out   (VALU fp32, LDS score strip)
//   4) out = attn_out @ w_proj + b_proj        (MFMA GEMM, dtype-flag output)
// ---------------------------------------------------------------------------

typedef __bf16 bf16_t;
typedef bf16_t bf16x8 __attribute__((ext_vector_type(8)));
typedef bf16_t bf16x4 __attribute__((ext_vector_type(4)));
typedef float  floatx4 __attribute__((ext_vector_type(4)));

#define SEQ_T   2048
#define NHEAD   16
#define HDIM    64
#define EMB     1024
#define WIN     256
#define QB      16
#define SCALE_F 0.125f

// ---------------------------------------------------------------------------
// dtype detector: for bf16 arrays, the low 16 bits of each 32b word are a
// bf16 value ~N(0,1) -> exponent field tightly clustered near 127 (~99% in
// [100,150]). For fp32 arrays those bits are mantissa noise (~20% in range).
// ---------------------------------------------------------------------------
__global__ __launch_bounds__(256) void detect_dtype(
    const unsigned int* __restrict__ w, int nwords, int* __restrict__ flag)
{
    __shared__ int cnt_s;
    if (threadIdx.x == 0) cnt_s = 0;
    __syncthreads();
    int c = 0;
    for (int i = threadIdx.x; i < nwords; i += 256) {
        const unsigned int e = (w[i] >> 7) & 0xffu;
        c += (e >= 100u && e <= 150u) ? 1 : 0;
    }
    atomicAdd(&cnt_s, c);
    __syncthreads();
    if (threadIdx.x == 0) *flag = (cnt_s * 2 > nwords) ? 1 : 0;
}

// ---------------------------------------------------------------------------
// canonicalize to bf16 (copy if already bf16, convert if fp32). n % 4 == 0.
// ---------------------------------------------------------------------------
__global__ __launch_bounds__(256) void canon_bf16(
    const void* __restrict__ src, bf16_t* __restrict__ dst, int n,
    const int* __restrict__ flag)
{
    const int f = *flag;
    const int i4 = (blockIdx.x * 256 + threadIdx.x) * 4;
    if (i4 >= n) return;
    bf16x4 v;
    if (f) {
        v = *(const bf16x4*)((const bf16_t*)src + i4);
    } else {
        const float4 x = *(const float4*)((const float*)src + i4);
        v[0] = (bf16_t)x.x; v[1] = (bf16_t)x.y;
        v[2] = (bf16_t)x.z; v[3] = (bf16_t)x.w;
    }
    *(bf16x4*)(dst + i4) = v;
}

// ---------------------------------------------------------------------------
// 64x64 tiled transpose with dtype-flagged load: Wt[n][k] = (bf16)W[k][n].
// ---------------------------------------------------------------------------
__global__ __launch_bounds__(256) void transpose_to_bf16(
    const void* __restrict__ W, bf16_t* __restrict__ Wt, int K, int N,
    const int* __restrict__ flag)
{
    __shared__ __align__(16) bf16_t tile[64][68];   // +4 pad breaks bank stride
    const int f  = *flag;
    const int n0 = blockIdx.x * 64;
    const int k0 = blockIdx.y * 64;
    const int tx = threadIdx.x & 15;   // 16 threads * 4 elems = 64 wide
    const int ty = threadIdx.x >> 4;   // 16 rows, stepped to 64

    #pragma unroll
    for (int r = ty; r < 64; r += 16) {
        bf16x4 v;
        const size_t base = (size_t)(k0 + r) * N + n0 + tx * 4;
        if (f) {
            v = *(const bf16x4*)((const bf16_t*)W + base);
        } else {
            const float4 x = *(const float4*)((const float*)W + base);
            v[0] = (bf16_t)x.x; v[1] = (bf16_t)x.y;
            v[2] = (bf16_t)x.z; v[3] = (bf16_t)x.w;
        }
        *(bf16x4*)&tile[r][tx * 4] = v;
    }
    __syncthreads();
    #pragma unroll
    for (int r = ty; r < 64; r += 16) {
        bf16x4 v;
        v[0] = tile[tx * 4 + 0][r];
        v[1] = tile[tx * 4 + 1][r];
        v[2] = tile[tx * 4 + 2][r];
        v[3] = tile[tx * 4 + 3][r];
        *(bf16x4*)(Wt + (size_t)(n0 + r) * K + k0 + tx * 4) = v;
    }
}

// ---------------------------------------------------------------------------
// C[M][N] = A[M][K] @ Bt[N][K]^T + bias[N]   (bf16 in, fp32 accumulate)
// Output: bf16 if (force_bf16 || *flag), else fp32.
// m97 structure: 128x128 tile, BK=32, 4 waves each computing 64x64,
// global_load_lds width-16 staging, mfma_f32_16x16x32_bf16.
// ---------------------------------------------------------------------------
#define BM 128
#define BN 128
#define BK 32

__global__ __launch_bounds__(256) void gemm_bt_bias(
    const bf16_t* __restrict__ A,
    const bf16_t* __restrict__ Bt,
    const bf16_t* __restrict__ bias,
    void* __restrict__ C,
    int M, int N, int K,
    int force_bf16, const int* __restrict__ flag)
{
    __shared__ __align__(16) bf16_t As[BM * BK];  // [m][k], 8 KB
    __shared__ __align__(16) bf16_t Bs[BN * BK];  // [n][k], 8 KB

    const int obf = force_bf16 | *flag;
    const int tid  = threadIdx.x;
    const int wave = tid >> 6;
    const int lane = tid & 63;
    const int m0 = blockIdx.y * BM;
    const int n0 = blockIdx.x * BN;
    const int wm = (wave >> 1) * 64;   // wave's 64x64 subtile
    const int wn = (wave & 1) * 64;

    floatx4 acc[4][4] = {};

    const int lr = lane >> 2;        // 0..15: row within 16-row chunk
    const int lc = (lane & 3) * 8;   // 0/8/16/24: col in elements

    for (int k0 = 0; k0 < K; k0 += BK) {
        // stage A and Bt tiles; lane i's 16B lands at ldsbase + i*16, which
        // matches As[(row0 + lane/4)*BK + (lane%4)*8] exactly (BK=32).
        #pragma unroll
        for (int c = 0; c < 2; ++c) {
            const int row0 = wave * 32 + c * 16;
            const bf16_t* ga = A  + (size_t)(m0 + row0 + lr) * K + k0 + lc;
            const bf16_t* gb = Bt + (size_t)(n0 + row0 + lr) * K + k0 + lc;
            __builtin_amdgcn_global_load_lds(
                (const __attribute__((address_space(1))) void*)ga,
                (__attribute__((address_space(3))) void*)(As + row0 * BK),
                16, 0, 0);
            __builtin_amdgcn_global_load_lds(
                (const __attribute__((address_space(1))) void*)gb,
                (__attribute__((address_space(3))) void*)(Bs + row0 * BK),
                16, 0, 0);
        }
        __syncthreads();

        // fragments: A[m=lane&15][k=(lane>>4)*8 + j]; B mirrored
        const bf16_t* pa = As + (wm + (lane & 15)) * BK + (lane >> 4) * 8;
        const bf16_t* pb = Bs + (wn + (lane & 15)) * BK + (lane >> 4) * 8;
        bf16x8 af[4], bfr[4];
        #pragma unroll
        for (int ff = 0; ff < 4; ++ff) {
            af[ff]  = *(const bf16x8*)(pa + ff * 16 * BK);
            bfr[ff] = *(const bf16x8*)(pb + ff * 16 * BK);
        }
        #pragma unroll
        for (int mf = 0; mf < 4; ++mf)
            #pragma unroll
            for (int nf = 0; nf < 4; ++nf)
                acc[mf][nf] = __builtin_amdgcn_mfma_f32_16x16x32_bf16(
                    af[mf], bfr[nf], acc[mf][nf], 0, 0, 0);
        __syncthreads();
    }

    // epilogue: C/D layout col=lane&15, row=(lane>>4)*4+reg
    const int col   = n0 + wn + (lane & 15);
    const int rbase = m0 + wm + (lane >> 4) * 4;
    #pragma unroll
    for (int nf = 0; nf < 4; ++nf) {
        const float bv = (float)bias[col + nf * 16];
        #pragma unroll
        for (int mf = 0; mf < 4; ++mf) {
            #pragma unroll
            for (int r = 0; r < 4; ++r) {
                const size_t idx =
                    (size_t)(rbase + mf * 16 + r) * N + col + nf * 16;
                const float val = acc[mf][nf][r] + bv;
                if (obf) ((bf16_t*)C)[idx] = (bf16_t)val;
                else     ((float*)C)[idx]  = val;
            }
        }
    }
}

// ---------------------------------------------------------------------------
// Windowed causal attention. One block = one (b, h, 16-query tile).
// qkv is [B*T][3E]; q at col h*64, k at E + h*64, v at 2E + h*64.
// Per 16-query block the union key range is <= 271 wide -> fp32 strip in LDS.
// ---------------------------------------------------------------------------
__global__ __launch_bounds__(256) void attn_win(
    const bf16_t* __restrict__ qkv,
    bf16_t* __restrict__ attn_out)
{
    __shared__ float Qs[QB][HDIM + 4];
    __shared__ float S[QB][WIN + QB];      // 16 x 272 fp32 score strip

    const int tid = threadIdx.x;
    const int qb  = blockIdx.x;
    const int h   = blockIdx.y;
    const int b   = blockIdx.z;
    const int i0  = qb * QB;
    const int klo = (i0 - (WIN - 1)) > 0 ? (i0 - (WIN - 1)) : 0;
    const int khi = i0 + QB - 1;
    const int nk  = khi - klo + 1;

    const size_t rowbase = (size_t)b * SEQ_T;

    // phase 1: load Q tile (bf16 -> fp32)
    for (int idx = tid; idx < QB * HDIM; idx += 256) {
        const int r = idx >> 6, d = idx & 63;
        Qs[r][d] = (float)qkv[(rowbase + i0 + r) * (3 * EMB) + h * HDIM + d];
    }
    __syncthreads();

    const int q   = tid >> 4;     // 0..15 query within tile
    const int sub = tid & 15;     // 16-lane subgroup lane
    const int i   = i0 + q;

    // phase 2: scores (masked -> -3e38; exp underflows to 0 like the ref)
    const bf16_t* Kbase = qkv + rowbase * (3 * EMB) + EMB + h * HDIM;
    for (int j = klo + sub; j <= khi; j += 16) {
        float s;
        if (j <= i && j > i - WIN) {
            s = 0.f;
            const bf16_t* kr = Kbase + (size_t)j * (3 * EMB);
            #pragma unroll
            for (int d = 0; d < HDIM; d += 8) {
                const bf16x8 kv = *(const bf16x8*)(kr + d);
                #pragma unroll
                for (int c = 0; c < 8; ++c)
                    s += (float)kv[c] * Qs[q][d + c];
            }
            s *= SCALE_F;
        } else {
            s = -3.0e38f;
        }
        S[q][j - klo] = s;
    }

    // phase 3: softmax across the strip; one 16-lane subgroup per query row
    float mx = -3.0e38f;
    for (int jj = sub; jj < nk; jj += 16) mx = fmaxf(mx, S[q][jj]);
    #pragma unroll
    for (int m = 8; m >= 1; m >>= 1) mx = fmaxf(mx, __shfl_xor(mx, m, 64));
    float sum = 0.f;
    for (int jj = sub; jj < nk; jj += 16) {
        const float e = __expf(S[q][jj] - mx);
        S[q][jj] = e;
        sum += e;
    }
    #pragma unroll
    for (int m = 8; m >= 1; m >>= 1) sum += __shfl_xor(sum, m, 64);
    const float rden = 1.0f / sum;
    __syncthreads();

    // phase 4: O[q][d0..d0+3] = sum_j P[q][j] * V[j][d]
    const int d0 = sub * 4;
    const bf16_t* V = qkv + (rowbase + klo) * (3 * EMB) + 2 * EMB + h * HDIM + d0;
    float o0 = 0.f, o1 = 0.f, o2 = 0.f, o3 = 0.f;
    for (int jj = 0; jj < nk; ++jj) {
        const float p = S[q][jj];
        const bf16x4 v = *(const bf16x4*)(V + (size_t)jj * (3 * EMB));
        o0 += p * (float)v[0];
        o1 += p * (float)v[1];
        o2 += p * (float)v[2];
        o3 += p * (float)v[3];
    }
    bf16x4 ov;
    ov[0] = (bf16_t)(o0 * rden);
    ov[1] = (bf16_t)(o1 * rden);
    ov[2] = (bf16_t)(o2 * rden);
    ov[3] = (bf16_t)(o3 * rden);
    *(bf16x4*)(attn_out + (rowbase + i) * EMB + h * HDIM + d0) = ov;
}

// ---------------------------------------------------------------------------
extern "C" void kernel_launch(void* const* d_in, const int* in_sizes, int n_in,
                              void* d_out, int out_size, void* d_ws, size_t ws_size,
                              hipStream_t stream)
{
    const void* hidden = d_in[0];   // [4096][1024]
    const void* w_attn = d_in[1];   // [1024][3072]
    const void* b_attn = d_in[2];   // [3072]
    const void* w_proj = d_in[3];   // [1024][1024]
    const void* b_proj = d_in[4];   // [1024]

    char* ws = (char*)d_ws;
    bf16_t* Wt_attn = (bf16_t*)(ws);                       // [3072][1024]  6 MB
    bf16_t* Wt_proj = (bf16_t*)(ws + (6u << 20));          // [1024][1024]  2 MB
    bf16_t* qkv     = (bf16_t*)(ws + (8u << 20));          // [4096][3072] 24 MB
    bf16_t* attn_o  = (bf16_t*)(ws + (32u << 20));         // [4096][1024]  8 MB
    bf16_t* Hc      = (bf16_t*)(ws + (40u << 20));         // [4096][1024]  8 MB
    bf16_t* bb_attn = (bf16_t*)(ws + (48u << 20));         // [3072]
    bf16_t* bb_proj = (bf16_t*)(ws + (48u << 20) + 8192);  // [1024]
    int*    flag    = (int*)   (ws + (48u << 20) + 16384);

    detect_dtype<<<1, 256, 0, stream>>>((const unsigned int*)hidden, 65536, flag);

    canon_bf16<<<4096, 256, 0, stream>>>(hidden, Hc, 4096 * 1024, flag);
    canon_bf16<<<3, 256, 0, stream>>>(b_attn, bb_attn, 3072, flag);
    canon_bf16<<<1, 256, 0, stream>>>(b_proj, bb_proj, 1024, flag);

    transpose_to_bf16<<<dim3(3072 / 64, 1024 / 64), 256, 0, stream>>>(
        w_attn, Wt_attn, 1024, 3072, flag);
    transpose_to_bf16<<<dim3(1024 / 64, 1024 / 64), 256, 0, stream>>>(
        w_proj, Wt_proj, 1024, 1024, flag);

    gemm_bt_bias<<<dim3(3072 / BN, 4096 / BM), 256, 0, stream>>>(
        Hc, Wt_attn, bb_attn, qkv, 4096, 3072, 1024, /*force_bf16=*/1, flag);

    attn_win<<<dim3(SEQ_T / QB, NHEAD, 2), 256, 0, stream>>>(qkv, attn_o);

    gemm_bt_bias<<<dim3(1024 / BN, 4096 / BM), 256, 0, stream>>>(
        attn_o, Wt_proj, bb_proj, (void*)d_out, 4096, 1024, 1024,
        /*force_bf16=*/0, flag);
}

// Round 3
// 243.202 us; speedup vs baseline: 2.4884x; 2.4884x over previous
//
#include <hip/hip_runtime.h>

// ---------------------------------------------------------------------------
// MaskedMultiHeadAttention: B=2, T=2048, E=1024, H=16, D=64, WINDOW=256
//
// Pipeline:
//   0) detect dtype -> flag (device-side; verified working in R2)
//   1) canonicalize hidden/biases to bf16; transpose w_attn/w_proj to bf16
//   2) qkv = hidden @ w_attn + b_attn          (MFMA bf16 GEMM, m97 structure)
//   3) MFMA flash attention (chunked strip)    (this round's rewrite)
//   4) out = attn_out @ w_proj + b_proj        (MFMA GEMM, dtype-flag output)
// ---------------------------------------------------------------------------

typedef __bf16 bf16_t;
typedef bf16_t bf16x8 __attribute__((ext_vector_type(8)));
typedef bf16_t bf16x4 __attribute__((ext_vector_type(4)));
typedef float  floatx4 __attribute__((ext_vector_type(4)));

#define SEQ_T   2048
#define NHEAD   16
#define HDIM    64
#define EMB     1024
#define WIN     256
#define SCALE_F 0.125f

// ---------------------------------------------------------------------------
__global__ __launch_bounds__(256) void detect_dtype(
    const unsigned int* __restrict__ w, int nwords, int* __restrict__ flag)
{
    __shared__ int cnt_s;
    if (threadIdx.x == 0) cnt_s = 0;
    __syncthreads();
    int c = 0;
    for (int i = threadIdx.x; i < nwords; i += 256) {
        const unsigned int e = (w[i] >> 7) & 0xffu;
        c += (e >= 100u && e <= 150u) ? 1 : 0;
    }
    atomicAdd(&cnt_s, c);
    __syncthreads();
    if (threadIdx.x == 0) *flag = (cnt_s * 2 > nwords) ? 1 : 0;
}

// ---------------------------------------------------------------------------
__global__ __launch_bounds__(256) void canon_bf16(
    const void* __restrict__ src, bf16_t* __restrict__ dst, int n,
    const int* __restrict__ flag)
{
    const int f = *flag;
    const int i4 = (blockIdx.x * 256 + threadIdx.x) * 4;
    if (i4 >= n) return;
    bf16x4 v;
    if (f) {
        v = *(const bf16x4*)((const bf16_t*)src + i4);
    } else {
        const float4 x = *(const float4*)((const float*)src + i4);
        v[0] = (bf16_t)x.x; v[1] = (bf16_t)x.y;
        v[2] = (bf16_t)x.z; v[3] = (bf16_t)x.w;
    }
    *(bf16x4*)(dst + i4) = v;
}

// ---------------------------------------------------------------------------
__global__ __launch_bounds__(256) void transpose_to_bf16(
    const void* __restrict__ W, bf16_t* __restrict__ Wt, int K, int N,
    const int* __restrict__ flag)
{
    __shared__ __align__(16) bf16_t tile[64][68];
    const int f  = *flag;
    const int n0 = blockIdx.x * 64;
    const int k0 = blockIdx.y * 64;
    const int tx = threadIdx.x & 15;
    const int ty = threadIdx.x >> 4;

    #pragma unroll
    for (int r = ty; r < 64; r += 16) {
        bf16x4 v;
        const size_t base = (size_t)(k0 + r) * N + n0 + tx * 4;
        if (f) {
            v = *(const bf16x4*)((const bf16_t*)W + base);
        } else {
            const float4 x = *(const float4*)((const float*)W + base);
            v[0] = (bf16_t)x.x; v[1] = (bf16_t)x.y;
            v[2] = (bf16_t)x.z; v[3] = (bf16_t)x.w;
        }
        *(bf16x4*)&tile[r][tx * 4] = v;
    }
    __syncthreads();
    #pragma unroll
    for (int r = ty; r < 64; r += 16) {
        bf16x4 v;
        v[0] = tile[tx * 4 + 0][r];
        v[1] = tile[tx * 4 + 1][r];
        v[2] = tile[tx * 4 + 2][r];
        v[3] = tile[tx * 4 + 3][r];
        *(bf16x4*)(Wt + (size_t)(n0 + r) * K + k0 + tx * 4) = v;
    }
}

// ---------------------------------------------------------------------------
// GEMM (unchanged from R2 — verified): C = A @ Bt^T + bias
// ---------------------------------------------------------------------------
#define BM 128
#define BN 128
#define BK 32

__global__ __launch_bounds__(256) void gemm_bt_bias(
    const bf16_t* __restrict__ A,
    const bf16_t* __restrict__ Bt,
    const bf16_t* __restrict__ bias,
    void* __restrict__ C,
    int M, int N, int K,
    int force_bf16, const int* __restrict__ flag)
{
    __shared__ __align__(16) bf16_t As[BM * BK];
    __shared__ __align__(16) bf16_t Bs[BN * BK];

    const int obf = force_bf16 | *flag;
    const int tid  = threadIdx.x;
    const int wave = tid >> 6;
    const int lane = tid & 63;
    const int m0 = blockIdx.y * BM;
    const int n0 = blockIdx.x * BN;
    const int wm = (wave >> 1) * 64;
    const int wn = (wave & 1) * 64;

    floatx4 acc[4][4] = {};

    const int lr = lane >> 2;
    const int lc = (lane & 3) * 8;

    for (int k0 = 0; k0 < K; k0 += BK) {
        #pragma unroll
        for (int c = 0; c < 2; ++c) {
            const int row0 = wave * 32 + c * 16;
            const bf16_t* ga = A  + (size_t)(m0 + row0 + lr) * K + k0 + lc;
            const bf16_t* gb = Bt + (size_t)(n0 + row0 + lr) * K + k0 + lc;
            __builtin_amdgcn_global_load_lds(
                (const __attribute__((address_space(1))) void*)ga,
                (__attribute__((address_space(3))) void*)(As + row0 * BK),
                16, 0, 0);
            __builtin_amdgcn_global_load_lds(
                (const __attribute__((address_space(1))) void*)gb,
                (__attribute__((address_space(3))) void*)(Bs + row0 * BK),
                16, 0, 0);
        }
        __syncthreads();

        const bf16_t* pa = As + (wm + (lane & 15)) * BK + (lane >> 4) * 8;
        const bf16_t* pb = Bs + (wn + (lane & 15)) * BK + (lane >> 4) * 8;
        bf16x8 af[4], bfr[4];
        #pragma unroll
        for (int ff = 0; ff < 4; ++ff) {
            af[ff]  = *(const bf16x8*)(pa + ff * 16 * BK);
            bfr[ff] = *(const bf16x8*)(pb + ff * 16 * BK);
        }
        #pragma unroll
        for (int mf = 0; mf < 4; ++mf)
            #pragma unroll
            for (int nf = 0; nf < 4; ++nf)
                acc[mf][nf] = __builtin_amdgcn_mfma_f32_16x16x32_bf16(
                    af[mf], bfr[nf], acc[mf][nf], 0, 0, 0);
        __syncthreads();
    }

    const int col   = n0 + wn + (lane & 15);
    const int rbase = m0 + wm + (lane >> 4) * 4;
    #pragma unroll
    for (int nf = 0; nf < 4; ++nf) {
        const float bv = (float)bias[col + nf * 16];
        #pragma unroll
        for (int mf = 0; mf < 4; ++mf) {
            #pragma unroll
            for (int r = 0; r < 4; ++r) {
                const size_t idx =
                    (size_t)(rbase + mf * 16 + r) * N + col + nf * 16;
                const float val = acc[mf][nf][r] + bv;
                if (obf) ((bf16_t*)C)[idx] = (bf16_t)val;
                else     ((float*)C)[idx]  = val;
            }
        }
    }
}

// ---------------------------------------------------------------------------
// MFMA flash attention. Block = (b, h, 64-query tile), 4 waves; wave w owns
// queries [i0+16w, i0+16w+16). Key strip c in [0,320) maps to key
// j = i0-256+c; processed in 2 chunks of 160.
//
// LDS (63,488 B total, fits the 64 KB static budget; 2 blocks/CU):
//   Ks  [160][64]  bf16, XOR-chunk-swizzled (swizzle done via the per-lane
//                  GLOBAL source address so global_load_lds dest stays
//                  contiguous; B-frag reads land 2-way = free)
//   Vt  [64][168]  bf16, V transposed, stride 168 (2-way reads)
//   Pst [4][16][168] bf16, per-wave private P strips
//
// MFMA layouts (HW-verified, guide §3):
//   A-frag: lane L holds A[m=L&15][k=(L>>4)*8+j]
//   B-frag: lane L holds B[k=(L>>4)*8+j][n=L&15], read from Bt[n][k]
//   C/D:    lane L reg r -> (row=(L>>4)*4+r, col=L&15)
// ---------------------------------------------------------------------------
#define CW   160
#define VT_S 168
#define P_S  168

__global__ __launch_bounds__(256) void attn_mfma(
    const bf16_t* __restrict__ qkv,
    bf16_t* __restrict__ attn_out)
{
    __shared__ __align__(16) bf16_t Ks[CW * 64];       // 20480 B
    __shared__ __align__(16) bf16_t Vt[64 * VT_S];     // 21504 B
    __shared__ __align__(16) bf16_t Pst[4][16 * P_S];  // 21504 B

    const int tid  = threadIdx.x;
    const int wave = tid >> 6;
    const int lane = tid & 63;
    const int quad = lane >> 4;
    const int n16  = lane & 15;

    const int i0 = blockIdx.x * 64;
    const int h  = blockIdx.y;
    const int b  = blockIdx.z;
    const size_t rowbase = (size_t)b * SEQ_T;
    const int kbase  = i0 - 256;          // strip col c -> key j = kbase + c
    const int iw     = 16 * wave;
    const int climit = 256 - i0;          // j >= 0  <=>  c >= climit

    // Q A-frags: lane reads Q[i0+iw+n16][32*s2 + quad*8 .. +7]
    const bf16_t* Qg = qkv + (rowbase + i0 + iw + n16) * (3 * EMB) + h * HDIM;
    bf16x8 qf[2];
    qf[0] = *(const bf16x8*)(Qg + quad * 8);
    qf[1] = *(const bf16x8*)(Qg + 32 + quad * 8);

    floatx4 Oac[4] = {};
    float m_run[4], l_run[4];
    #pragma unroll
    for (int rr = 0; rr < 4; ++rr) { m_run[rr] = -3.0e38f; l_run[rr] = 0.f; }

    for (int hc = 0; hc < 2; ++hc) {
        const int cbase = hc * CW;

        // --- V chunk -> registers (global reads; issued before the barrier)
        bf16x8 vreg[5];
        #pragma unroll
        for (int t = 0; t < 5; ++t) {
            const int idx = tid + 256 * t;          // 0..1279
            const int lc  = idx >> 3;               // 0..159
            const int d0  = (idx & 7) * 8;
            int j = kbase + cbase + lc; if (j < 0) j = 0;
            vreg[t] = *(const bf16x8*)(qkv + (rowbase + j) * (3 * EMB)
                                       + 2 * EMB + h * HDIM + d0);
        }

        __syncthreads();   // prior chunk's LDS fully consumed

        // --- K chunk -> LDS via global_load_lds, source-address swizzle:
        // stored chunk s of row lc holds global chunk s ^ (lc & 7)
        #pragma unroll
        for (int t = 0; t < 5; ++t) {
            const int lc0 = wave * 40 + t * 8;      // wave-uniform
            const int lcL = lc0 + (lane >> 3);
            int j = kbase + cbase + lcL; if (j < 0) j = 0;
            const int g = (lane & 7) ^ (lcL & 7);
            const bf16_t* src = qkv + (rowbase + j) * (3 * EMB)
                                + EMB + h * HDIM + g * 8;
            __builtin_amdgcn_global_load_lds(
                (const __attribute__((address_space(1))) void*)src,
                (__attribute__((address_space(3))) void*)(Ks + lc0 * 64),
                16, 0, 0);
        }

        // --- V chunk transposed -> LDS
        #pragma unroll
        for (int t = 0; t < 5; ++t) {
            const int idx = tid + 256 * t;
            const int lc  = idx >> 3;
            const int d0  = (idx & 7) * 8;
            #pragma unroll
            for (int e = 0; e < 8; ++e)
                Vt[(d0 + e) * VT_S + lc] = vreg[t][e];
        }

        __syncthreads();   // staging visible (drains vmcnt for load_lds too)

        // --- QK^T: 10 tiles of 16 keys, K-dim 64 = 2 slices of 32
        floatx4 sc[10];
        #pragma unroll
        for (int tt = 0; tt < 10; ++tt) {
            sc[tt] = (floatx4){0.f, 0.f, 0.f, 0.f};
            #pragma unroll
            for (int s2 = 0; s2 < 2; ++s2) {
                const int lc = 16 * tt + n16;
                const int ch = (4 * s2 + quad) ^ (lc & 7);
                const bf16x8 kf = *(const bf16x8*)(Ks + lc * 64 + ch * 8);
                sc[tt] = __builtin_amdgcn_mfma_f32_16x16x32_bf16(
                    qf[s2], kf, sc[tt], 0, 0, 0);
            }
        }

        // --- mask + scale (valid: r < c-iw <= r+256 and j>=0)
        #pragma unroll
        for (int tt = 0; tt < 10; ++tt) {
            const int c  = cbase + 16 * tt + n16;
            const int cw = c - iw;
            #pragma unroll
            for (int rr = 0; rr < 4; ++rr) {
                const int r = quad * 4 + rr;
                const bool valid = (cw > r) && (cw <= r + 256) && (c >= climit);
                sc[tt][rr] = valid ? sc[tt][rr] * SCALE_F : -3.0e38f;
            }
        }

        // --- chunk row-max (regs + 4x shfl_xor within the 16-lane group)
        float cm[4];
        #pragma unroll
        for (int rr = 0; rr < 4; ++rr) {
            cm[rr] = -3.0e38f;
            #pragma unroll
            for (int tt = 0; tt < 10; ++tt) cm[rr] = fmaxf(cm[rr], sc[tt][rr]);
            #pragma unroll
            for (int m = 8; m >= 1; m >>= 1)
                cm[rr] = fmaxf(cm[rr], __shfl_xor(cm[rr], m, 64));
        }

        // --- online-softmax update (m/l live in the O-owning lanes)
        #pragma unroll
        for (int rr = 0; rr < 4; ++rr) {
            const float mnew  = fmaxf(m_run[rr], cm[rr]);
            const float alpha = __expf(m_run[rr] - mnew);  // -inf - -inf -> 0 -> 1
            m_run[rr] = mnew;
            l_run[rr] *= alpha;
            #pragma unroll
            for (int nt = 0; nt < 4; ++nt) Oac[nt][rr] *= alpha;
        }

        // --- exp + sum + P strip write (masked entries -> exactly 0)
        float psum[4] = {0.f, 0.f, 0.f, 0.f};
        #pragma unroll
        for (int tt = 0; tt < 10; ++tt) {
            #pragma unroll
            for (int rr = 0; rr < 4; ++rr) {
                const float s = sc[tt][rr];
                const float e = (s > -1.0e38f) ? __expf(s - m_run[rr]) : 0.f;
                psum[rr] += e;
                Pst[wave][(quad * 4 + rr) * P_S + 16 * tt + n16] = (bf16_t)e;
            }
        }
        #pragma unroll
        for (int rr = 0; rr < 4; ++rr) {
            #pragma unroll
            for (int m = 8; m >= 1; m >>= 1)
                psum[rr] += __shfl_xor(psum[rr], m, 64);
            l_run[rr] += psum[rr];
        }

        __syncthreads();   // P strips + (paranoia) cross-lane LDS ordering

        // --- PV: O += P(16x160) @ V(160x64); 5 k-slices x 4 col-tiles
        #pragma unroll
        for (int ks = 0; ks < 5; ++ks) {
            const bf16x8 paf = *(const bf16x8*)(
                &Pst[wave][n16 * P_S + ks * 32 + quad * 8]);
            #pragma unroll
            for (int nt = 0; nt < 4; ++nt) {
                const bf16x8 vbf = *(const bf16x8*)(
                    Vt + (nt * 16 + n16) * VT_S + ks * 32 + quad * 8);
                Oac[nt] = __builtin_amdgcn_mfma_f32_16x16x32_bf16(
                    paf, vbf, Oac[nt], 0, 0, 0);
            }
        }
    }

    // --- epilogue: O / l, C/D layout scatter (coalesced over n16)
    #pragma unroll
    for (int rr = 0; rr < 4; ++rr) {
        const float rden = 1.0f / l_run[rr];
        const size_t row = rowbase + i0 + iw + quad * 4 + rr;
        #pragma unroll
        for (int nt = 0; nt < 4; ++nt) {
            attn_out[row * EMB + h * HDIM + nt * 16 + n16] =
                (bf16_t)(Oac[nt][rr] * rden);
        }
    }
}

// ---------------------------------------------------------------------------
extern "C" void kernel_launch(void* const* d_in, const int* in_sizes, int n_in,
                              void* d_out, int out_size, void* d_ws, size_t ws_size,
                              hipStream_t stream)
{
    const void* hidden = d_in[0];
    const void* w_attn = d_in[1];
    const void* b_attn = d_in[2];
    const void* w_proj = d_in[3];
    const void* b_proj = d_in[4];

    char* ws = (char*)d_ws;
    bf16_t* Wt_attn = (bf16_t*)(ws);                       // [3072][1024]
    bf16_t* Wt_proj = (bf16_t*)(ws + (6u << 20));          // [1024][1024]
    bf16_t* qkv     = (bf16_t*)(ws + (8u << 20));          // [4096][3072]
    bf16_t* attn_o  = (bf16_t*)(ws + (32u << 20));         // [4096][1024]
    bf16_t* Hc      = (bf16_t*)(ws + (40u << 20));         // [4096][1024]
    bf16_t* bb_attn = (bf16_t*)(ws + (48u << 20));
    bf16_t* bb_proj = (bf16_t*)(ws + (48u << 20) + 8192);
    int*    flag    = (int*)   (ws + (48u << 20) + 16384);

    detect_dtype<<<1, 256, 0, stream>>>((const unsigned int*)hidden, 65536, flag);

    canon_bf16<<<4096, 256, 0, stream>>>(hidden, Hc, 4096 * 1024, flag);
    canon_bf16<<<3, 256, 0, stream>>>(b_attn, bb_attn, 3072, flag);
    canon_bf16<<<1, 256, 0, stream>>>(b_proj, bb_proj, 1024, flag);

    transpose_to_bf16<<<dim3(3072 / 64, 1024 / 64), 256, 0, stream>>>(
        w_attn, Wt_attn, 1024, 3072, flag);
    transpose_to_bf16<<<dim3(1024 / 64, 1024 / 64), 256, 0, stream>>>(
        w_proj, Wt_proj, 1024, 1024, flag);

    gemm_bt_bias<<<dim3(3072 / BN, 4096 / BM), 256, 0, stream>>>(
        Hc, Wt_attn, bb_attn, qkv, 4096, 3072, 1024, 1, flag);

    attn_mfma<<<dim3(SEQ_T / 64, NHEAD, 2), 256, 0, stream>>>(qkv, attn_o);

    gemm_bt_bias<<<dim3(1024 / BN, 4096 / BM), 256, 0, stream>>>(
        attn_o, Wt_proj, bb_proj, (void*)d_out, 4096, 1024, 1024, 0, flag);
}

// Round 4
// 201.663 us; speedup vs baseline: 3.0009x; 1.2060x over previous
//
#include <hip/hip_runtime.h>

// ---------------------------------------------------------------------------
// MaskedMultiHeadAttention: B=2, T=2048, E=1024, H=16, D=64, WINDOW=256
//
// Pipeline:
//   0) detect dtype -> flag (device-side; R4: 1024 thr + uint4, ~2.5us)
//   1) canonicalize hidden/biases to bf16; transpose w_attn/w_proj to bf16
//   2) qkv = hidden @ w_attn + b_attn     (MFMA GEMM, R4: dbuf + swizzle)
//   3) MFMA flash attention               (verified R3)
//   4) out = attn_out @ w_proj + b_proj   (MFMA GEMM, dtype-flag output)
// ---------------------------------------------------------------------------

typedef __bf16 bf16_t;
typedef bf16_t bf16x8 __attribute__((ext_vector_type(8)));
typedef bf16_t bf16x4 __attribute__((ext_vector_type(4)));
typedef float  floatx4 __attribute__((ext_vector_type(4)));

#define SEQ_T   2048
#define NHEAD   16
#define HDIM    64
#define EMB     1024
#define WIN     256
#define SCALE_F 0.125f

// ---------------------------------------------------------------------------
// dtype detector. bf16 arrays: low 16 bits of each word are bf16 ~N(0,1),
// exponent in [100,150] ~99% of the time; fp32 arrays: mantissa noise ~20%.
// 1024 threads, uint4 loads, 4096 vectors (16384 words), wave-reduced.
// ---------------------------------------------------------------------------
__global__ __launch_bounds__(1024) void detect_dtype(
    const uint4* __restrict__ w, int nvec, int* __restrict__ flag)
{
    __shared__ int cnt_s;
    if (threadIdx.x == 0) cnt_s = 0;
    __syncthreads();
    int c = 0;
    for (int i = threadIdx.x; i < nvec; i += 1024) {
        const uint4 v = w[i];
        #pragma unroll
        for (int e = 0; e < 4; ++e) {
            const unsigned int word = (&v.x)[e];
            const unsigned int ex = (word >> 7) & 0xffu;
            c += (ex >= 100u && ex <= 150u) ? 1 : 0;
        }
    }
    #pragma unroll
    for (int m = 32; m >= 1; m >>= 1) c += __shfl_xor(c, m, 64);
    if ((threadIdx.x & 63) == 0) atomicAdd(&cnt_s, c);
    __syncthreads();
    if (threadIdx.x == 0) *flag = (cnt_s * 2 > nvec * 4) ? 1 : 0;
}

// ---------------------------------------------------------------------------
__global__ __launch_bounds__(256) void canon_bf16(
    const void* __restrict__ src, bf16_t* __restrict__ dst, int n,
    const int* __restrict__ flag)
{
    const int f = *flag;
    const int i4 = (blockIdx.x * 256 + threadIdx.x) * 4;
    if (i4 >= n) return;
    bf16x4 v;
    if (f) {
        v = *(const bf16x4*)((const bf16_t*)src + i4);
    } else {
        const float4 x = *(const float4*)((const float*)src + i4);
        v[0] = (bf16_t)x.x; v[1] = (bf16_t)x.y;
        v[2] = (bf16_t)x.z; v[3] = (bf16_t)x.w;
    }
    *(bf16x4*)(dst + i4) = v;
}

// ---------------------------------------------------------------------------
__global__ __launch_bounds__(256) void transpose_to_bf16(
    const void* __restrict__ W, bf16_t* __restrict__ Wt, int K, int N,
    const int* __restrict__ flag)
{
    __shared__ __align__(16) bf16_t tile[64][68];
    const int f  = *flag;
    const int n0 = blockIdx.x * 64;
    const int k0 = blockIdx.y * 64;
    const int tx = threadIdx.x & 15;
    const int ty = threadIdx.x >> 4;

    #pragma unroll
    for (int r = ty; r < 64; r += 16) {
        bf16x4 v;
        const size_t base = (size_t)(k0 + r) * N + n0 + tx * 4;
        if (f) {
            v = *(const bf16x4*)((const bf16_t*)W + base);
        } else {
            const float4 x = *(const float4*)((const float*)W + base);
            v[0] = (bf16_t)x.x; v[1] = (bf16_t)x.y;
            v[2] = (bf16_t)x.z; v[3] = (bf16_t)x.w;
        }
        *(bf16x4*)&tile[r][tx * 4] = v;
    }
    __syncthreads();
    #pragma unroll
    for (int r = ty; r < 64; r += 16) {
        bf16x4 v;
        v[0] = tile[tx * 4 + 0][r];
        v[1] = tile[tx * 4 + 1][r];
        v[2] = tile[tx * 4 + 2][r];
        v[3] = tile[tx * 4 + 3][r];
        *(bf16x4*)(Wt + (size_t)(n0 + r) * K + k0 + tx * 4) = v;
    }
}

// ---------------------------------------------------------------------------
// C[M][N] = A[M][K] @ Bt[N][K]^T + bias[N]   (bf16 in, fp32 accumulate)
// R4: double-buffered global_load_lds staging (prefetch tile k+1 after the
// barrier so the barrier's vmcnt drain covers loads issued a full compute
// phase earlier) + XOR source-address swizzle (stored chunk p of row r holds
// global chunk p ^ (r&3); fragment reads drop from 8-way to 4-way conflicts).
// ---------------------------------------------------------------------------
#define BM 128
#define BN 128
#define BK 32

__global__ __launch_bounds__(256) void gemm_bt_bias(
    const bf16_t* __restrict__ A,
    const bf16_t* __restrict__ Bt,
    const bf16_t* __restrict__ bias,
    void* __restrict__ C,
    int M, int N, int K,
    int force_bf16, const int* __restrict__ flag)
{
    __shared__ __align__(16) bf16_t As[2][BM * BK];  // 2 x 8 KB
    __shared__ __align__(16) bf16_t Bs[2][BN * BK];  // 2 x 8 KB

    const int obf = force_bf16 | *flag;
    const int tid  = threadIdx.x;
    const int wave = tid >> 6;
    const int lane = tid & 63;
    const int quad = lane >> 4;
    const int n16  = lane & 15;
    const int m0 = blockIdx.y * BM;
    const int n0 = blockIdx.x * BN;
    const int wm = (wave >> 1) * 64;
    const int wn = (wave & 1) * 64;

    floatx4 acc[4][4] = {};

    const int lr   = lane >> 2;                          // row within 16-chunk
    const int lcsw = ((lane & 3) ^ (lr & 3)) * 8;        // swizzled src chunk

    // stage K-tile kk into buffer buf (LDS dest stays lane-contiguous)
    auto stage = [&](int buf, int kk) {
        #pragma unroll
        for (int c = 0; c < 2; ++c) {
            const int row0 = wave * 32 + c * 16;         // multiple of 16
            const bf16_t* ga = A  + (size_t)(m0 + row0 + lr) * K + kk + lcsw;
            const bf16_t* gb = Bt + (size_t)(n0 + row0 + lr) * K + kk + lcsw;
            __builtin_amdgcn_global_load_lds(
                (const __attribute__((address_space(1))) void*)ga,
                (__attribute__((address_space(3))) void*)(&As[buf][row0 * BK]),
                16, 0, 0);
            __builtin_amdgcn_global_load_lds(
                (const __attribute__((address_space(1))) void*)gb,
                (__attribute__((address_space(3))) void*)(&Bs[buf][row0 * BK]),
                16, 0, 0);
        }
    };

    stage(0, 0);
    int cur = 0;
    const int rsw = (n16 & 3);   // fragment row & 3 (rows wm/wn + f*16 + n16)

    for (int k0 = 0; k0 < K; k0 += BK) {
        __syncthreads();                 // drains the stage() issued last iter
        if (k0 + BK < K) stage(cur ^ 1, k0 + BK);

        const bf16_t* pa = &As[cur][(wm + n16) * BK + ((quad ^ rsw) * 8)];
        const bf16_t* pb = &Bs[cur][(wn + n16) * BK + ((quad ^ rsw) * 8)];
        bf16x8 af[4], bfr[4];
        #pragma unroll
        for (int ff = 0; ff < 4; ++ff) {
            af[ff]  = *(const bf16x8*)(pa + ff * 16 * BK);
            bfr[ff] = *(const bf16x8*)(pb + ff * 16 * BK);
        }
        #pragma unroll
        for (int mf = 0; mf < 4; ++mf)
            #pragma unroll
            for (int nf = 0; nf < 4; ++nf)
                acc[mf][nf] = __builtin_amdgcn_mfma_f32_16x16x32_bf16(
                    af[mf], bfr[nf], acc[mf][nf], 0, 0, 0);
        cur ^= 1;
    }

    const int col   = n0 + wn + n16;
    const int rbase = m0 + wm + quad * 4;
    #pragma unroll
    for (int nf = 0; nf < 4; ++nf) {
        const float bv = (float)bias[col + nf * 16];
        #pragma unroll
        for (int mf = 0; mf < 4; ++mf) {
            #pragma unroll
            for (int r = 0; r < 4; ++r) {
                const size_t idx =
                    (size_t)(rbase + mf * 16 + r) * N + col + nf * 16;
                const float val = acc[mf][nf][r] + bv;
                if (obf) ((bf16_t*)C)[idx] = (bf16_t)val;
                else     ((float*)C)[idx]  = val;
            }
        }
    }
}

// ---------------------------------------------------------------------------
// MFMA flash attention (verified R3, unchanged). Block = (b,h,64-query tile).
// ---------------------------------------------------------------------------
#define CW   160
#define VT_S 168
#define P_S  168

__global__ __launch_bounds__(256) void attn_mfma(
    const bf16_t* __restrict__ qkv,
    bf16_t* __restrict__ attn_out)
{
    __shared__ __align__(16) bf16_t Ks[CW * 64];       // 20480 B
    __shared__ __align__(16) bf16_t Vt[64 * VT_S];     // 21504 B
    __shared__ __align__(16) bf16_t Pst[4][16 * P_S];  // 21504 B

    const int tid  = threadIdx.x;
    const int wave = tid >> 6;
    const int lane = tid & 63;
    const int quad = lane >> 4;
    const int n16  = lane & 15;

    const int i0 = blockIdx.x * 64;
    const int h  = blockIdx.y;
    const int b  = blockIdx.z;
    const size_t rowbase = (size_t)b * SEQ_T;
    const int kbase  = i0 - 256;
    const int iw     = 16 * wave;
    const int climit = 256 - i0;

    const bf16_t* Qg = qkv + (rowbase + i0 + iw + n16) * (3 * EMB) + h * HDIM;
    bf16x8 qf[2];
    qf[0] = *(const bf16x8*)(Qg + quad * 8);
    qf[1] = *(const bf16x8*)(Qg + 32 + quad * 8);

    floatx4 Oac[4] = {};
    float m_run[4], l_run[4];
    #pragma unroll
    for (int rr = 0; rr < 4; ++rr) { m_run[rr] = -3.0e38f; l_run[rr] = 0.f; }

    for (int hc = 0; hc < 2; ++hc) {
        const int cbase = hc * CW;

        bf16x8 vreg[5];
        #pragma unroll
        for (int t = 0; t < 5; ++t) {
            const int idx = tid + 256 * t;
            const int lc  = idx >> 3;
            const int d0  = (idx & 7) * 8;
            int j = kbase + cbase + lc; if (j < 0) j = 0;
            vreg[t] = *(const bf16x8*)(qkv + (rowbase + j) * (3 * EMB)
                                       + 2 * EMB + h * HDIM + d0);
        }

        __syncthreads();

        #pragma unroll
        for (int t = 0; t < 5; ++t) {
            const int lc0 = wave * 40 + t * 8;
            const int lcL = lc0 + (lane >> 3);
            int j = kbase + cbase + lcL; if (j < 0) j = 0;
            const int g = (lane & 7) ^ (lcL & 7);
            const bf16_t* src = qkv + (rowbase + j) * (3 * EMB)
                                + EMB + h * HDIM + g * 8;
            __builtin_amdgcn_global_load_lds(
                (const __attribute__((address_space(1))) void*)src,
                (__attribute__((address_space(3))) void*)(Ks + lc0 * 64),
                16, 0, 0);
        }

        #pragma unroll
        for (int t = 0; t < 5; ++t) {
            const int idx = tid + 256 * t;
            const int lc  = idx >> 3;
            const int d0  = (idx & 7) * 8;
            #pragma unroll
            for (int e = 0; e < 8; ++e)
                Vt[(d0 + e) * VT_S + lc] = vreg[t][e];
        }

        __syncthreads();

        floatx4 sc[10];
        #pragma unroll
        for (int tt = 0; tt < 10; ++tt) {
            sc[tt] = (floatx4){0.f, 0.f, 0.f, 0.f};
            #pragma unroll
            for (int s2 = 0; s2 < 2; ++s2) {
                const int lc = 16 * tt + n16;
                const int ch = (4 * s2 + quad) ^ (lc & 7);
                const bf16x8 kf = *(const bf16x8*)(Ks + lc * 64 + ch * 8);
                sc[tt] = __builtin_amdgcn_mfma_f32_16x16x32_bf16(
                    qf[s2], kf, sc[tt], 0, 0, 0);
            }
        }

        #pragma unroll
        for (int tt = 0; tt < 10; ++tt) {
            const int c  = cbase + 16 * tt + n16;
            const int cw = c - iw;
            #pragma unroll
            for (int rr = 0; rr < 4; ++rr) {
                const int r = quad * 4 + rr;
                const bool valid = (cw > r) && (cw <= r + 256) && (c >= climit);
                sc[tt][rr] = valid ? sc[tt][rr] * SCALE_F : -3.0e38f;
            }
        }

        float cm[4];
        #pragma unroll
        for (int rr = 0; rr < 4; ++rr) {
            cm[rr] = -3.0e38f;
            #pragma unroll
            for (int tt = 0; tt < 10; ++tt) cm[rr] = fmaxf(cm[rr], sc[tt][rr]);
            #pragma unroll
            for (int m = 8; m >= 1; m >>= 1)
                cm[rr] = fmaxf(cm[rr], __shfl_xor(cm[rr], m, 64));
        }

        #pragma unroll
        for (int rr = 0; rr < 4; ++rr) {
            const float mnew  = fmaxf(m_run[rr], cm[rr]);
            const float alpha = __expf(m_run[rr] - mnew);
            m_run[rr] = mnew;
            l_run[rr] *= alpha;
            #pragma unroll
            for (int nt = 0; nt < 4; ++nt) Oac[nt][rr] *= alpha;
        }

        float psum[4] = {0.f, 0.f, 0.f, 0.f};
        #pragma unroll
        for (int tt = 0; tt < 10; ++tt) {
            #pragma unroll
            for (int rr = 0; rr < 4; ++rr) {
                const float s = sc[tt][rr];
                const float e = (s > -1.0e38f) ? __expf(s - m_run[rr]) : 0.f;
                psum[rr] += e;
                Pst[wave][(quad * 4 + rr) * P_S + 16 * tt + n16] = (bf16_t)e;
            }
        }
        #pragma unroll
        for (int rr = 0; rr < 4; ++rr) {
            #pragma unroll
            for (int m = 8; m >= 1; m >>= 1)
                psum[rr] += __shfl_xor(psum[rr], m, 64);
            l_run[rr] += psum[rr];
        }

        __syncthreads();

        #pragma unroll
        for (int ks = 0; ks < 5; ++ks) {
            const bf16x8 paf = *(const bf16x8*)(
                &Pst[wave][n16 * P_S + ks * 32 + quad * 8]);
            #pragma unroll
            for (int nt = 0; nt < 4; ++nt) {
                const bf16x8 vbf = *(const bf16x8*)(
                    Vt + (nt * 16 + n16) * VT_S + ks * 32 + quad * 8);
                Oac[nt] = __builtin_amdgcn_mfma_f32_16x16x32_bf16(
                    paf, vbf, Oac[nt], 0, 0, 0);
            }
        }
    }

    #pragma unroll
    for (int rr = 0; rr < 4; ++rr) {
        const float rden = 1.0f / l_run[rr];
        const size_t row = rowbase + i0 + iw + quad * 4 + rr;
        #pragma unroll
        for (int nt = 0; nt < 4; ++nt) {
            attn_out[row * EMB + h * HDIM + nt * 16 + n16] =
                (bf16_t)(Oac[nt][rr] * rden);
        }
    }
}

// ---------------------------------------------------------------------------
extern "C" void kernel_launch(void* const* d_in, const int* in_sizes, int n_in,
                              void* d_out, int out_size, void* d_ws, size_t ws_size,
                              hipStream_t stream)
{
    const void* hidden = d_in[0];
    const void* w_attn = d_in[1];
    const void* b_attn = d_in[2];
    const void* w_proj = d_in[3];
    const void* b_proj = d_in[4];

    char* ws = (char*)d_ws;
    bf16_t* Wt_attn = (bf16_t*)(ws);                       // [3072][1024]
    bf16_t* Wt_proj = (bf16_t*)(ws + (6u << 20));          // [1024][1024]
    bf16_t* qkv     = (bf16_t*)(ws + (8u << 20));          // [4096][3072]
    bf16_t* attn_o  = (bf16_t*)(ws + (32u << 20));         // [4096][1024]
    bf16_t* Hc      = (bf16_t*)(ws + (40u << 20));         // [4096][1024]
    bf16_t* bb_attn = (bf16_t*)(ws + (48u << 20));
    bf16_t* bb_proj = (bf16_t*)(ws + (48u << 20) + 8192);
    int*    flag    = (int*)   (ws + (48u << 20) + 16384);

    detect_dtype<<<1, 1024, 0, stream>>>((const uint4*)hidden, 4096, flag);

    canon_bf16<<<4096, 256, 0, stream>>>(hidden, Hc, 4096 * 1024, flag);
    canon_bf16<<<3, 256, 0, stream>>>(b_attn, bb_attn, 3072, flag);
    canon_bf16<<<1, 256, 0, stream>>>(b_proj, bb_proj, 1024, flag);

    transpose_to_bf16<<<dim3(3072 / 64, 1024 / 64), 256, 0, stream>>>(
        w_attn, Wt_attn, 1024, 3072, flag);
    transpose_to_bf16<<<dim3(1024 / 64, 1024 / 64), 256, 0, stream>>>(
        w_proj, Wt_proj, 1024, 1024, flag);

    gemm_bt_bias<<<dim3(3072 / BN, 4096 / BM), 256, 0, stream>>>(
        Hc, Wt_attn, bb_attn, qkv, 4096, 3072, 1024, 1, flag);

    attn_mfma<<<dim3(SEQ_T / 64, NHEAD, 2), 256, 0, stream>>>(qkv, attn_o);

    gemm_bt_bias<<<dim3(1024 / BN, 4096 / BM), 256, 0, stream>>>(
        attn_o, Wt_proj, bb_proj, (void*)d_out, 4096, 1024, 1024, 0, flag);
}

// Round 5
// 190.850 us; speedup vs baseline: 3.1709x; 1.0567x over previous
//
#include <hip/hip_runtime.h>

// ---------------------------------------------------------------------------
// MaskedMultiHeadAttention: B=2, T=2048, E=1024, H=16, D=64, WINDOW=256
//
// Pipeline:
//   0) detect dtype -> flag (device-side, ~2us)
//   1) canonicalize hidden/biases to bf16; transpose w_attn/w_proj to bf16
//   2) qkv = hidden @ w_attn + b_attn     (MFMA GEMM, R5: BK=64 + XOR swizzle)
//   3) MFMA flash attention               (verified R3)
//   4) out = attn_out @ w_proj + b_proj   (MFMA GEMM, BN=64 -> 512 blocks)
// ---------------------------------------------------------------------------

typedef __bf16 bf16_t;
typedef bf16_t bf16x8 __attribute__((ext_vector_type(8)));
typedef bf16_t bf16x4 __attribute__((ext_vector_type(4)));
typedef float  floatx4 __attribute__((ext_vector_type(4)));

#define SEQ_T   2048
#define NHEAD   16
#define HDIM    64
#define EMB     1024
#define WIN     256
#define SCALE_F 0.125f

// ---------------------------------------------------------------------------
__global__ __launch_bounds__(1024) void detect_dtype(
    const uint4* __restrict__ w, int nvec, int* __restrict__ flag)
{
    __shared__ int cnt_s;
    if (threadIdx.x == 0) cnt_s = 0;
    __syncthreads();
    int c = 0;
    for (int i = threadIdx.x; i < nvec; i += 1024) {
        const uint4 v = w[i];
        #pragma unroll
        for (int e = 0; e < 4; ++e) {
            const unsigned int word = (&v.x)[e];
            const unsigned int ex = (word >> 7) & 0xffu;
            c += (ex >= 100u && ex <= 150u) ? 1 : 0;
        }
    }
    #pragma unroll
    for (int m = 32; m >= 1; m >>= 1) c += __shfl_xor(c, m, 64);
    if ((threadIdx.x & 63) == 0) atomicAdd(&cnt_s, c);
    __syncthreads();
    if (threadIdx.x == 0) *flag = (cnt_s * 2 > nvec * 4) ? 1 : 0;
}

// ---------------------------------------------------------------------------
__global__ __launch_bounds__(256) void canon_bf16(
    const void* __restrict__ src, bf16_t* __restrict__ dst, int n,
    const int* __restrict__ flag)
{
    const int f = *flag;
    const int i4 = (blockIdx.x * 256 + threadIdx.x) * 4;
    if (i4 >= n) return;
    bf16x4 v;
    if (f) {
        v = *(const bf16x4*)((const bf16_t*)src + i4);
    } else {
        const float4 x = *(const float4*)((const float*)src + i4);
        v[0] = (bf16_t)x.x; v[1] = (bf16_t)x.y;
        v[2] = (bf16_t)x.z; v[3] = (bf16_t)x.w;
    }
    *(bf16x4*)(dst + i4) = v;
}

// ---------------------------------------------------------------------------
__global__ __launch_bounds__(256) void transpose_to_bf16(
    const void* __restrict__ W, bf16_t* __restrict__ Wt, int K, int N,
    const int* __restrict__ flag)
{
    __shared__ __align__(16) bf16_t tile[64][68];
    const int f  = *flag;
    const int n0 = blockIdx.x * 64;
    const int k0 = blockIdx.y * 64;
    const int tx = threadIdx.x & 15;
    const int ty = threadIdx.x >> 4;

    #pragma unroll
    for (int r = ty; r < 64; r += 16) {
        bf16x4 v;
        const size_t base = (size_t)(k0 + r) * N + n0 + tx * 4;
        if (f) {
            v = *(const bf16x4*)((const bf16_t*)W + base);
        } else {
            const float4 x = *(const float4*)((const float*)W + base);
            v[0] = (bf16_t)x.x; v[1] = (bf16_t)x.y;
            v[2] = (bf16_t)x.z; v[3] = (bf16_t)x.w;
        }
        *(bf16x4*)&tile[r][tx * 4] = v;
    }
    __syncthreads();
    #pragma unroll
    for (int r = ty; r < 64; r += 16) {
        bf16x4 v;
        v[0] = tile[tx * 4 + 0][r];
        v[1] = tile[tx * 4 + 1][r];
        v[2] = tile[tx * 4 + 2][r];
        v[3] = tile[tx * 4 + 3][r];
        *(bf16x4*)(Wt + (size_t)(n0 + r) * K + k0 + tx * 4) = v;
    }
}

// ---------------------------------------------------------------------------
// C[M][N] = A[M][K] @ Bt[N][K]^T + bias[N]   (bf16 in, fp32 accumulate)
// R5: BK=64 single-buffer (16 K-iters, 32 MFMA/wave/iter -> half the
// vmcnt(0) barrier drains of BK=32), XOR-swizzled LDS (row stride 128 B is
// bank-0-aligned, so stored chunk p of row r holds global chunk p^(r&7);
// the swizzle lives in the per-lane GLOBAL source address g=(lane&7)^(lane>>3)
// so the global_load_lds LDS dest stays lane-contiguous). Fragment reads then
// spread over all 32 banks (2 lanes/bank = free).
// Templated on BNt: 128 for QKV (768 blocks), 64 for proj (512 blocks).
// ---------------------------------------------------------------------------
template<int BNt>
__global__ __launch_bounds__(256) void gemm_bt_bias(
    const bf16_t* __restrict__ A,
    const bf16_t* __restrict__ Bt,
    const bf16_t* __restrict__ bias,
    void* __restrict__ C,
    int M, int N, int K,
    int force_bf16, const int* __restrict__ flag)
{
    constexpr int BMt = 128;
    constexpr int NF  = BNt / 32;            // n-frags per wave (wave n = BNt/2)
    __shared__ __align__(16) bf16_t As[BMt * 64];   // 16 KB
    __shared__ __align__(16) bf16_t Bs[BNt * 64];   // 16/8 KB

    const int obf  = force_bf16 | *flag;
    const int tid  = threadIdx.x;
    const int wave = tid >> 6;
    const int lane = tid & 63;
    const int quad = lane >> 4;
    const int n16  = lane & 15;
    const int m0 = blockIdx.y * BMt;
    const int n0 = blockIdx.x * BNt;
    const int wm = (wave >> 1) * 64;
    const int wn = (wave & 1) * (BNt / 2);

    floatx4 acc[4][NF] = {};

    // staging: each global_load_lds moves 8 rows x 64 cols; lane L covers
    // row (L>>3), stored chunk (L&7) <- global chunk (L&7)^(L>>3)
    const int lr = lane >> 3;
    const int g8 = ((lane & 7) ^ lr) * 8;

    // fragment read base: row = w? + ff*16 + n16, chunk (4s+quad)^(n16&7)
    const int csw = (quad ^ (n16 & 7)) * 8;   // slice 0; slice 1 adds 4^... below

    for (int k0 = 0; k0 < K; k0 += 64) {
        #pragma unroll
        for (int t = 0; t < BMt / 32; ++t) {
            const int row0 = wave * (BMt / 4) + t * 8;
            const bf16_t* ga = A + (size_t)(m0 + row0 + lr) * K + k0 + g8;
            __builtin_amdgcn_global_load_lds(
                (const __attribute__((address_space(1))) void*)ga,
                (__attribute__((address_space(3))) void*)(As + row0 * 64),
                16, 0, 0);
        }
        #pragma unroll
        for (int t = 0; t < BNt / 32; ++t) {
            const int row0 = wave * (BNt / 4) + t * 8;
            const bf16_t* gb = Bt + (size_t)(n0 + row0 + lr) * K + k0 + g8;
            __builtin_amdgcn_global_load_lds(
                (const __attribute__((address_space(1))) void*)gb,
                (__attribute__((address_space(3))) void*)(Bs + row0 * 64),
                16, 0, 0);
        }
        __syncthreads();

        #pragma unroll
        for (int s = 0; s < 2; ++s) {
            const int ch = (((4 * s + quad) ^ (n16 & 7)) * 8);
            const bf16_t* pa = As + (wm + n16) * 64 + ch;
            const bf16_t* pb = Bs + (wn + n16) * 64 + ch;
            bf16x8 af[4], bfr[NF];
            #pragma unroll
            for (int ff = 0; ff < 4; ++ff)
                af[ff] = *(const bf16x8*)(pa + ff * 16 * 64);
            #pragma unroll
            for (int ff = 0; ff < NF; ++ff)
                bfr[ff] = *(const bf16x8*)(pb + ff * 16 * 64);
            #pragma unroll
            for (int mf = 0; mf < 4; ++mf)
                #pragma unroll
                for (int nf = 0; nf < NF; ++nf)
                    acc[mf][nf] = __builtin_amdgcn_mfma_f32_16x16x32_bf16(
                        af[mf], bfr[nf], acc[mf][nf], 0, 0, 0);
        }
        __syncthreads();
    }

    const int col   = n0 + wn + n16;
    const int rbase = m0 + wm + quad * 4;
    #pragma unroll
    for (int nf = 0; nf < NF; ++nf) {
        const float bv = (float)bias[col + nf * 16];
        #pragma unroll
        for (int mf = 0; mf < 4; ++mf) {
            #pragma unroll
            for (int r = 0; r < 4; ++r) {
                const size_t idx =
                    (size_t)(rbase + mf * 16 + r) * N + col + nf * 16;
                const float val = acc[mf][nf][r] + bv;
                if (obf) ((bf16_t*)C)[idx] = (bf16_t)val;
                else     ((float*)C)[idx]  = val;
            }
        }
    }
}

// ---------------------------------------------------------------------------
// MFMA flash attention (verified R3, unchanged). Block = (b,h,64-query tile).
// ---------------------------------------------------------------------------
#define CW   160
#define VT_S 168
#define P_S  168

__global__ __launch_bounds__(256) void attn_mfma(
    const bf16_t* __restrict__ qkv,
    bf16_t* __restrict__ attn_out)
{
    __shared__ __align__(16) bf16_t Ks[CW * 64];       // 20480 B
    __shared__ __align__(16) bf16_t Vt[64 * VT_S];     // 21504 B
    __shared__ __align__(16) bf16_t Pst[4][16 * P_S];  // 21504 B

    const int tid  = threadIdx.x;
    const int wave = tid >> 6;
    const int lane = tid & 63;
    const int quad = lane >> 4;
    const int n16  = lane & 15;

    const int i0 = blockIdx.x * 64;
    const int h  = blockIdx.y;
    const int b  = blockIdx.z;
    const size_t rowbase = (size_t)b * SEQ_T;
    const int kbase  = i0 - 256;
    const int iw     = 16 * wave;
    const int climit = 256 - i0;

    const bf16_t* Qg = qkv + (rowbase + i0 + iw + n16) * (3 * EMB) + h * HDIM;
    bf16x8 qf[2];
    qf[0] = *(const bf16x8*)(Qg + quad * 8);
    qf[1] = *(const bf16x8*)(Qg + 32 + quad * 8);

    floatx4 Oac[4] = {};
    float m_run[4], l_run[4];
    #pragma unroll
    for (int rr = 0; rr < 4; ++rr) { m_run[rr] = -3.0e38f; l_run[rr] = 0.f; }

    for (int hc = 0; hc < 2; ++hc) {
        const int cbase = hc * CW;

        bf16x8 vreg[5];
        #pragma unroll
        for (int t = 0; t < 5; ++t) {
            const int idx = tid + 256 * t;
            const int lc  = idx >> 3;
            const int d0  = (idx & 7) * 8;
            int j = kbase + cbase + lc; if (j < 0) j = 0;
            vreg[t] = *(const bf16x8*)(qkv + (rowbase + j) * (3 * EMB)
                                       + 2 * EMB + h * HDIM + d0);
        }

        __syncthreads();

        #pragma unroll
        for (int t = 0; t < 5; ++t) {
            const int lc0 = wave * 40 + t * 8;
            const int lcL = lc0 + (lane >> 3);
            int j = kbase + cbase + lcL; if (j < 0) j = 0;
            const int g = (lane & 7) ^ (lcL & 7);
            const bf16_t* src = qkv + (rowbase + j) * (3 * EMB)
                                + EMB + h * HDIM + g * 8;
            __builtin_amdgcn_global_load_lds(
                (const __attribute__((address_space(1))) void*)src,
                (__attribute__((address_space(3))) void*)(Ks + lc0 * 64),
                16, 0, 0);
        }

        #pragma unroll
        for (int t = 0; t < 5; ++t) {
            const int idx = tid + 256 * t;
            const int lc  = idx >> 3;
            const int d0  = (idx & 7) * 8;
            #pragma unroll
            for (int e = 0; e < 8; ++e)
                Vt[(d0 + e) * VT_S + lc] = vreg[t][e];
        }

        __syncthreads();

        floatx4 sc[10];
        #pragma unroll
        for (int tt = 0; tt < 10; ++tt) {
            sc[tt] = (floatx4){0.f, 0.f, 0.f, 0.f};
            #pragma unroll
            for (int s2 = 0; s2 < 2; ++s2) {
                const int lc = 16 * tt + n16;
                const int ch = (4 * s2 + quad) ^ (lc & 7);
                const bf16x8 kf = *(const bf16x8*)(Ks + lc * 64 + ch * 8);
                sc[tt] = __builtin_amdgcn_mfma_f32_16x16x32_bf16(
                    qf[s2], kf, sc[tt], 0, 0, 0);
            }
        }

        #pragma unroll
        for (int tt = 0; tt < 10; ++tt) {
            const int c  = cbase + 16 * tt + n16;
            const int cw = c - iw;
            #pragma unroll
            for (int rr = 0; rr < 4; ++rr) {
                const int r = quad * 4 + rr;
                const bool valid = (cw > r) && (cw <= r + 256) && (c >= climit);
                sc[tt][rr] = valid ? sc[tt][rr] * SCALE_F : -3.0e38f;
            }
        }

        float cm[4];
        #pragma unroll
        for (int rr = 0; rr < 4; ++rr) {
            cm[rr] = -3.0e38f;
            #pragma unroll
            for (int tt = 0; tt < 10; ++tt) cm[rr] = fmaxf(cm[rr], sc[tt][rr]);
            #pragma unroll
            for (int m = 8; m >= 1; m >>= 1)
                cm[rr] = fmaxf(cm[rr], __shfl_xor(cm[rr], m, 64));
        }

        #pragma unroll
        for (int rr = 0; rr < 4; ++rr) {
            const float mnew  = fmaxf(m_run[rr], cm[rr]);
            const float alpha = __expf(m_run[rr] - mnew);
            m_run[rr] = mnew;
            l_run[rr] *= alpha;
            #pragma unroll
            for (int nt = 0; nt < 4; ++nt) Oac[nt][rr] *= alpha;
        }

        float psum[4] = {0.f, 0.f, 0.f, 0.f};
        #pragma unroll
        for (int tt = 0; tt < 10; ++tt) {
            #pragma unroll
            for (int rr = 0; rr < 4; ++rr) {
                const float s = sc[tt][rr];
                const float e = (s > -1.0e38f) ? __expf(s - m_run[rr]) : 0.f;
                psum[rr] += e;
                Pst[wave][(quad * 4 + rr) * P_S + 16 * tt + n16] = (bf16_t)e;
            }
        }
        #pragma unroll
        for (int rr = 0; rr < 4; ++rr) {
            #pragma unroll
            for (int m = 8; m >= 1; m >>= 1)
                psum[rr] += __shfl_xor(psum[rr], m, 64);
            l_run[rr] += psum[rr];
        }

        __syncthreads();

        #pragma unroll
        for (int ks = 0; ks < 5; ++ks) {
            const bf16x8 paf = *(const bf16x8*)(
                &Pst[wave][n16 * P_S + ks * 32 + quad * 8]);
            #pragma unroll
            for (int nt = 0; nt < 4; ++nt) {
                const bf16x8 vbf = *(const bf16x8*)(
                    Vt + (nt * 16 + n16) * VT_S + ks * 32 + quad * 8);
                Oac[nt] = __builtin_amdgcn_mfma_f32_16x16x32_bf16(
                    paf, vbf, Oac[nt], 0, 0, 0);
            }
        }
    }

    #pragma unroll
    for (int rr = 0; rr < 4; ++rr) {
        const float rden = 1.0f / l_run[rr];
        const size_t row = rowbase + i0 + iw + quad * 4 + rr;
        #pragma unroll
        for (int nt = 0; nt < 4; ++nt) {
            attn_out[row * EMB + h * HDIM + nt * 16 + n16] =
                (bf16_t)(Oac[nt][rr] * rden);
        }
    }
}

// ---------------------------------------------------------------------------
extern "C" void kernel_launch(void* const* d_in, const int* in_sizes, int n_in,
                              void* d_out, int out_size, void* d_ws, size_t ws_size,
                              hipStream_t stream)
{
    const void* hidden = d_in[0];
    const void* w_attn = d_in[1];
    const void* b_attn = d_in[2];
    const void* w_proj = d_in[3];
    const void* b_proj = d_in[4];

    char* ws = (char*)d_ws;
    bf16_t* Wt_attn = (bf16_t*)(ws);                       // [3072][1024]
    bf16_t* Wt_proj = (bf16_t*)(ws + (6u << 20));          // [1024][1024]
    bf16_t* qkv     = (bf16_t*)(ws + (8u << 20));          // [4096][3072]
    bf16_t* attn_o  = (bf16_t*)(ws + (32u << 20));         // [4096][1024]
    bf16_t* Hc      = (bf16_t*)(ws + (40u << 20));         // [4096][1024]
    bf16_t* bb_attn = (bf16_t*)(ws + (48u << 20));
    bf16_t* bb_proj = (bf16_t*)(ws + (48u << 20) + 8192);
    int*    flag    = (int*)   (ws + (48u << 20) + 16384);

    detect_dtype<<<1, 1024, 0, stream>>>((const uint4*)hidden, 4096, flag);

    canon_bf16<<<4096, 256, 0, stream>>>(hidden, Hc, 4096 * 1024, flag);
    canon_bf16<<<3, 256, 0, stream>>>(b_attn, bb_attn, 3072, flag);
    canon_bf16<<<1, 256, 0, stream>>>(b_proj, bb_proj, 1024, flag);

    transpose_to_bf16<<<dim3(3072 / 64, 1024 / 64), 256, 0, stream>>>(
        w_attn, Wt_attn, 1024, 3072, flag);
    transpose_to_bf16<<<dim3(1024 / 64, 1024 / 64), 256, 0, stream>>>(
        w_proj, Wt_proj, 1024, 1024, flag);

    gemm_bt_bias<128><<<dim3(3072 / 128, 4096 / 128), 256, 0, stream>>>(
        Hc, Wt_attn, bb_attn, qkv, 4096, 3072, 1024, 1, flag);

    attn_mfma<<<dim3(SEQ_T / 64, NHEAD, 2), 256, 0, stream>>>(qkv, attn_o);

    gemm_bt_bias<64><<<dim3(1024 / 64, 4096 / 128), 256, 0, stream>>>(
        attn_o, Wt_proj, bb_proj, (void*)d_out, 4096, 1024, 1024, 0, flag);
}